// Round 3
// baseline (13811.531 us; speedup 1.0000x reference)
//
#include <hip/hip_runtime.h>
#include <hip/hip_bf16.h>
#include <math.h>

// DAGNN r13:
//  - spmm3: dest-bucket LDS accumulation + source-range sweep.
//    Edges packed (src<<8 | dest&255) in segments keyed (bucket, range);
//    block per bucket (391 blocks, 2/CU co-resident), facc[256][68] f32 in
//    LDS via ds_add_f32. Edge-parallel: 8 lanes/edge dwordx4 gather,
//    2-deep pipeline. Ranges of 16384 src (2.1 MB bf16 rows) swept in order
//    -> per-XCD L2 residency for the gather (r12's idea, minus its per-dest
//    CSR serialization which caused the 216us/hop regression).
//  - build simplified: transposed counts (cnt[key][blk]) let passB scatter
//    straight into final segment order; passC/second-scan/pairs removed.
//  - mlp_fused unchanged.

#define NBLK 256    // blocks in passA/passB
#define RS 520      // LDS region stride in ushorts (mlp)
#define NR 8        // source ranges
#define RSH 14      // range = src >> RSH (16384 nodes = 2.1 MB bf16 rows)
#define NBKMAX 3200 // max (bucket,range) keys; N<=102400

__device__ inline float bf2f(unsigned short u) {
    union { unsigned int i; float f; } v; v.i = ((unsigned int)u) << 16; return v.f;
}
__device__ inline unsigned short f2bf(float f) {
    __hip_bfloat16 b = __float2bfloat16(f);
    union { __hip_bfloat16 b; unsigned short u; } v; v.b = b; return v.u;
}
__device__ inline float bflo(unsigned u) {
    union { unsigned i; float f; } v; v.i = u << 16; return v.f;
}
__device__ inline float bfhi(unsigned u) {
    union { unsigned i; float f; } v; v.i = u & 0xffff0000u; return v.f;
}

typedef __attribute__((ext_vector_type(8))) short bf16x8;
typedef __attribute__((ext_vector_type(16))) float f32x16;

// ---- edge dtype detection: stride 1 (int32) or 2 (int64 low words) ----
__global__ void detect_kernel(const unsigned* __restrict__ e, int* __restrict__ sflag) {
    __shared__ int any;
    if (threadIdx.x == 0) any = 0;
    __syncthreads();
    unsigned nz = 0;
    int t = threadIdx.x;
    for (int i = 0; i < 8; ++i) nz |= e[(size_t)(t * 8 + i) * 2 + 1];
    if (nz) atomicOr(&any, 1);
    __syncthreads();
    if (t == 0) *sflag = any ? 1 : 2;
}

// ---- passA: per-block histogram over (bucket,range) keys; transposed write
//      cnt[key*NBLK + blk] so the scan yields final segment-contiguous bases ----
__global__ void passA_kernel(const int* __restrict__ eidx, const int* __restrict__ sflag,
                             int* __restrict__ blk_cnt, int E, int NBK, int EPB) {
    __shared__ int lh[NBKMAX];
    int t = threadIdx.x, blk = blockIdx.x;
    for (int i = t; i < NBK; i += 256) lh[i] = 0;
    __syncthreads();
    int s = *sflag;
    int base = blk * EPB;
    int end = base + EPB; if (end > E) end = E;
    for (int e = base + t; e < end; e += 256) {
        int r = eidx[(size_t)s * (size_t)e];
        int c = eidx[(size_t)s * (size_t)(E + e)];
        int rr = r >> RSH; if (rr > NR - 1) rr = NR - 1;
        atomicAdd(&lh[((c >> 8) << 3) | rr], 1);
    }
    __syncthreads();
    for (int i = t; i < NBK; i += 256)
        blk_cnt[(size_t)i * NBLK + blk] = lh[i];
}

// ---- scans ----
__global__ void scan1_kernel(const int* __restrict__ in, int* __restrict__ out,
                             int* __restrict__ bsums, int n) {
    __shared__ int s[256];
    int t = threadIdx.x;
    int idx = blockIdx.x * 1024 + t * 4;
    int x0 = (idx + 0 < n) ? in[idx + 0] : 0;
    int x1 = (idx + 1 < n) ? in[idx + 1] : 0;
    int x2 = (idx + 2 < n) ? in[idx + 2] : 0;
    int x3 = (idx + 3 < n) ? in[idx + 3] : 0;
    int lsum = x0 + x1 + x2 + x3;
    s[t] = lsum;
    __syncthreads();
    for (int o = 1; o < 256; o <<= 1) {
        int v = (t >= o) ? s[t - o] : 0;
        __syncthreads();
        if (t >= o) s[t] += v;
        __syncthreads();
    }
    int excl = s[t] - lsum;
    if (idx + 0 < n) out[idx + 0] = excl;
    if (idx + 1 < n) out[idx + 1] = excl + x0;
    if (idx + 2 < n) out[idx + 2] = excl + x0 + x1;
    if (idx + 3 < n) out[idx + 3] = excl + x0 + x1 + x2;
    if (t == 255) bsums[blockIdx.x] = s[255];
}

__global__ void scan2g_kernel(int* __restrict__ bsums, int nb) {
    __shared__ int part[256];
    int t = threadIdx.x;
    int v[4]; int run = 0;
    #pragma unroll
    for (int j = 0; j < 4; ++j) {
        int i = t * 4 + j;
        int x = (i < nb) ? bsums[i] : 0;
        v[j] = run; run += x;
    }
    part[t] = run;
    __syncthreads();
    for (int o = 1; o < 256; o <<= 1) {
        int x = (t >= o) ? part[t - o] : 0;
        __syncthreads();
        if (t >= o) part[t] += x;
        __syncthreads();
    }
    int excl = part[t] - run;
    #pragma unroll
    for (int j = 0; j < 4; ++j) {
        int i = t * 4 + j;
        if (i < nb) bsums[i] = excl + v[j];
    }
}

__global__ void scan3_kernel(int* __restrict__ arr, const int* __restrict__ bsums,
                             int n, int total) {
    int t = threadIdx.x;
    int idx = blockIdx.x * 1024 + t * 4;
    int add = bsums[blockIdx.x];
    #pragma unroll
    for (int i = 0; i < 4; ++i)
        if (idx + i < n) arr[idx + i] += add;
    if (blockIdx.x == 0 && t == 0) arr[n] = total;
}

// ---- passB: scatter edges directly into final segment order.
//      cursor[key] starts at pbase[key*NBLK + blk]; writes packed u32. ----
__global__ void passB_kernel(const int* __restrict__ eidx, const int* __restrict__ sflag,
                             const int* __restrict__ pbase, unsigned* __restrict__ seg,
                             int E, int NBK, int EPB) {
    __shared__ int lcur[NBKMAX];
    int t = threadIdx.x, blk = blockIdx.x;
    for (int i = t; i < NBK; i += 256) lcur[i] = pbase[(size_t)i * NBLK + blk];
    __syncthreads();
    int s = *sflag;
    int base = blk * EPB;
    int end = base + EPB; if (end > E) end = E;
    for (int e = base + t; e < end; e += 256) {
        int r = eidx[(size_t)s * (size_t)e];
        int c = eidx[(size_t)s * (size_t)(E + e)];
        int rr = r >> RSH; if (rr > NR - 1) rr = NR - 1;
        int pos = atomicAdd(&lcur[((c >> 8) << 3) | rr], 1);
        seg[pos] = ((unsigned)r << 8) | (unsigned)(c & 255);
    }
}

// ---- passD: per-dest degree from the bucket's contiguous segments + dinv ----
__global__ void passD_kernel(const unsigned* __restrict__ seg, const int* __restrict__ pbase,
                             float* __restrict__ dinv, int N) {
    __shared__ int lcnt[256];
    int b = blockIdx.x, t = threadIdx.x;
    lcnt[t] = 0;
    __syncthreads();
    int w0 = pbase[(size_t)(b * NR) * NBLK];
    int w1 = pbase[(size_t)(b * NR + NR) * NBLK];
    for (int i = w0 + t; i < w1; i += 256)
        atomicAdd(&lcnt[seg[i] & 255], 1);
    __syncthreads();
    int node = b * 256 + t;
    if (node < N) dinv[node] = rsqrtf((float)(lcnt[t] + 1));  // self-loop adds 1
}

// ---- weight convert to fragment-major: Wf[(k>>3)*Nn*8 + n*8 + (k&7)] = bf16(W[k][n]) ----
__global__ void wconv_kernel(const float* __restrict__ W, unsigned short* __restrict__ Wf,
                             int K, int Nn) {
    int i = blockIdx.x * blockDim.x + threadIdx.x;
    if (i >= K * Nn) return;
    int k = i / Nn, n = i - k * Nn;
    Wf[(size_t)(k >> 3) * Nn * 8 + n * 8 + (k & 7)] = f2bf(W[i]);
}

// ---- fused MLP: h = relu(x@W1+b1)@W2+b2 ; out = sigmoid(h.pw+pb)*h ;
//      g0 = bf16(dinv*h).  BM=64 rows/block, 256 thr (4 waves). ----
__global__ __launch_bounds__(256, 4) void mlp_fused(
        const float* __restrict__ x,
        const unsigned short* __restrict__ W1f,   // frag-major [k>>3][256 n][8]
        const float* __restrict__ b1,
        const unsigned short* __restrict__ W2f,   // frag-major [k>>3][64 n][8]
        const float* __restrict__ b2,
        const float* __restrict__ dinv,
        const float* __restrict__ pw, const float* __restrict__ pb,
        float* __restrict__ out, unsigned short* __restrict__ g,
        int M) {
    __shared__ unsigned short xfrag[4 * RS];    // region = (k&31)>>3
    __shared__ unsigned short h1frag[32 * RS];  // region = ch>>3 (stage-2 k)
    __shared__ float pools[2][2][2][16];        // [rt2][ct2][half][reg]

    int tid = threadIdx.x;
    int wave = tid >> 6, lane = tid & 63;
    int half = lane >> 5, l31 = lane & 31;
    int rt = wave & 1;          // stage-1 row tile (32 rows)
    int cw = wave >> 1;         // stage-1 col half (128 cols)
    int bm = blockIdx.x * 64;

    f32x16 acc1[4] = {};

    float4 xv[2];
    #pragma unroll
    for (int i = 0; i < 2; ++i) {
        int f = i * 256 + tid;
        int row = f >> 3, c4 = (f & 7) * 4;
        int grow = bm + row;
        xv[i] = (grow < M) ? *(const float4*)(x + (size_t)grow * 256 + c4)
                           : make_float4(0.f, 0.f, 0.f, 0.f);
    }

    for (int it = 0; it < 8; ++it) {
        #pragma unroll
        for (int i = 0; i < 2; ++i) {
            int f = i * 256 + tid;
            int row = f >> 3, c4 = (f & 7) * 4;
            int region = c4 >> 3, off = c4 & 7;
            ushort4 u;
            u.x = f2bf(xv[i].x); u.y = f2bf(xv[i].y);
            u.z = f2bf(xv[i].z); u.w = f2bf(xv[i].w);
            *(ushort4*)&xfrag[region * RS + row * 8 + off] = u;
        }
        __syncthreads();
        if (it < 7) {
            int k0 = (it + 1) * 32;
            #pragma unroll
            for (int i = 0; i < 2; ++i) {
                int f = i * 256 + tid;
                int row = f >> 3, c4 = (f & 7) * 4;
                int grow = bm + row;
                xv[i] = (grow < M) ? *(const float4*)(x + (size_t)grow * 256 + k0 + c4)
                                   : make_float4(0.f, 0.f, 0.f, 0.f);
            }
        }
        #pragma unroll
        for (int s = 0; s < 2; ++s) {
            int region = it * 4 + s * 2 + half;          // k>>3 of this fragment
            bf16x8 a = *(bf16x8*)&xfrag[(s * 2 + half) * RS + (rt * 32 + l31) * 8];
            #pragma unroll
            for (int j = 0; j < 4; ++j) {
                int ch = cw * 128 + j * 32 + l31;
                bf16x8 b = *(const bf16x8*)(W1f + (size_t)region * 2048 + ch * 8);
                acc1[j] = __builtin_amdgcn_mfma_f32_32x32x16_bf16(a, b, acc1[j], 0, 0, 0);
            }
        }
        __syncthreads();
    }

    // bias + relu, write h1 tile to LDS in stage-2 A-fragment layout
    #pragma unroll
    for (int j = 0; j < 4; ++j) {
        int ch = cw * 128 + j * 32 + l31;     // stage-2 k index
        float bb = b1[ch];
        int region = ch >> 3, off = ch & 7;
        #pragma unroll
        for (int reg = 0; reg < 16; ++reg) {
            int rowin = (reg & 3) + 8 * (reg >> 2) + 4 * half;
            int row = rt * 32 + rowin;
            float v = fmaxf(acc1[j][reg] + bb, 0.f);
            h1frag[region * RS + row * 8 + off] = f2bf(v);
        }
    }
    __syncthreads();

    // stage 2 on all 4 waves: wave = rt2*2 + ct2 tile (32 rows x 32 cols)
    int rt2 = wave >> 1, ct2 = wave & 1;
    f32x16 acc2 = {};
    #pragma unroll
    for (int s = 0; s < 16; ++s) {
        bf16x8 a = *(bf16x8*)&h1frag[(s * 2 + half) * RS + (rt2 * 32 + l31) * 8];
        bf16x8 b = *(const bf16x8*)(W2f + (size_t)(s * 2 + half) * 512 + (ct2 * 32 + l31) * 8);
        acc2 = __builtin_amdgcn_mfma_f32_32x32x16_bf16(a, b, acc2, 0, 0, 0);
    }

    float bb = b2[ct2 * 32 + l31];
    float pwv = pw[ct2 * 32 + l31];
    float pbv = pb[0];
    float hreg[16];
    #pragma unroll
    for (int reg = 0; reg < 16; ++reg) {
        float h = acc2[reg] + bb;
        hreg[reg] = h;
        float d = h * pwv;
        d += __shfl_xor(d, 1, 64);
        d += __shfl_xor(d, 2, 64);
        d += __shfl_xor(d, 4, 64);
        d += __shfl_xor(d, 8, 64);
        d += __shfl_xor(d, 16, 64);
        if (l31 == 0) pools[rt2][ct2][half][reg] = d;
    }
    __syncthreads();
    #pragma unroll
    for (int reg = 0; reg < 16; ++reg) {
        int rowin = (reg & 3) + 8 * (reg >> 2) + 4 * half;
        int row = bm + rt2 * 32 + rowin;
        float d = pools[rt2][0][half][reg] + pools[rt2][1][half][reg];
        float sg = 1.f / (1.f + __expf(-(d + pbv)));
        float h = hreg[reg];
        if (row < M) {
            float dv = dinv[row];
            out[(size_t)row * 64 + ct2 * 32 + l31] = sg * h;
            g[(size_t)row * 64 + ct2 * 32 + l31]   = f2bf(dv * h);
        }
    }
}

// ---- one hop (r13): block per dest bucket, LDS f32 accumulation,
//      source-range sweep for per-XCD L2 residency of the gather. ----
__global__ __launch_bounds__(512, 4) void spmm3_kernel(
        const int* __restrict__ pbase, const unsigned* __restrict__ seg,
        const float* __restrict__ dinv,
        const unsigned* __restrict__ gin,      // bf16x2 dwords, 32/row
        unsigned* __restrict__ gout,
        float* __restrict__ out,
        const float* __restrict__ pw, const float* __restrict__ pb,
        int n) {
    __shared__ float facc[256 * 68];   // stride 68 dwords spreads LDS banks
    __shared__ float pwl[64];
    __shared__ float pbl;
    int t = threadIdx.x;
    int b = blockIdx.x;
    for (int i = t; i < 256 * 68; i += 512) facc[i] = 0.f;
    if (t < 64) pwl[t] = pw[t];
    if (t == 64) pbl = pb[0];
    __syncthreads();

    int g = t >> 3;     // edge slot within block iteration (0..63)
    int q = t & 7;      // dword quad: dwords 4q..4q+3 = channels 8q..8q+7
    int segb = b * NR;
    for (int r = 0; r < NR; ++r) {
        int e0 = __builtin_amdgcn_readfirstlane(pbase[(size_t)(segb + r) * NBLK]);
        int e1 = __builtin_amdgcn_readfirstlane(pbase[(size_t)(segb + r + 1) * NBLK]);
        int e = e0 + g;
        if (e < e1) {
            unsigned pk = __builtin_nontemporal_load(seg + e);
            uint4 v = *(const uint4*)(gin + (size_t)(pk >> 8) * 32 + q * 4);
            for (;;) {
                int en = e + 64;
                bool more = en < e1;
                unsigned pkn = 0u; uint4 vn;
                if (more) {
                    pkn = __builtin_nontemporal_load(seg + en);
                    vn = *(const uint4*)(gin + (size_t)(pkn >> 8) * 32 + q * 4);
                }
                float* fb = &facc[(pk & 255u) * 68 + q * 8];
                atomicAdd(&fb[0], bflo(v.x)); atomicAdd(&fb[1], bfhi(v.x));
                atomicAdd(&fb[2], bflo(v.y)); atomicAdd(&fb[3], bfhi(v.y));
                atomicAdd(&fb[4], bflo(v.z)); atomicAdd(&fb[5], bfhi(v.z));
                atomicAdd(&fb[6], bflo(v.w)); atomicAdd(&fb[7], bfhi(v.w));
                if (!more) break;
                pk = pkn; v = vn; e = en;
            }
        }
    }
    __syncthreads();

    // epilogue: 2 threads per dest (hh = channel half)
    int d2 = t >> 1, hh = t & 1;
    int c = b * 256 + d2;
    if (c >= n) return;
    float dc = dinv[c];
    float h[32];
    const unsigned* grow = gin + (size_t)c * 32 + hh * 16;
    #pragma unroll
    for (int u = 0; u < 4; ++u) {
        uint4 sv = *(const uint4*)(grow + u * 4);   // self-loop (prescaled)
        h[u*8+0] = bflo(sv.x); h[u*8+1] = bfhi(sv.x);
        h[u*8+2] = bflo(sv.y); h[u*8+3] = bfhi(sv.y);
        h[u*8+4] = bflo(sv.z); h[u*8+5] = bfhi(sv.z);
        h[u*8+6] = bflo(sv.w); h[u*8+7] = bfhi(sv.w);
    }
    const float* fb = &facc[d2 * 68 + hh * 32];
    float d = 0.f;
    #pragma unroll
    for (int k = 0; k < 32; ++k) {
        float hv = dc * (fb[k] + h[k]);
        h[k] = hv;
        d += hv * pwl[hh * 32 + k];
    }
    d += __shfl_xor(d, 1, 64);   // partner thread shares the dest
    float sg = 1.f / (1.f + __expf(-(d + pbl)));
    unsigned* gr = gout + (size_t)c * 32 + hh * 16;
    #pragma unroll
    for (int u = 0; u < 4; ++u) {
        uint4 gw;
        gw.x = (unsigned)f2bf(dc*h[u*8+0]) | ((unsigned)f2bf(dc*h[u*8+1]) << 16);
        gw.y = (unsigned)f2bf(dc*h[u*8+2]) | ((unsigned)f2bf(dc*h[u*8+3]) << 16);
        gw.z = (unsigned)f2bf(dc*h[u*8+4]) | ((unsigned)f2bf(dc*h[u*8+5]) << 16);
        gw.w = (unsigned)f2bf(dc*h[u*8+6]) | ((unsigned)f2bf(dc*h[u*8+7]) << 16);
        *(uint4*)(gr + u * 4) = gw;
    }
    float* orow = out + (size_t)c * 64 + hh * 32;
    #pragma unroll
    for (int u = 0; u < 8; ++u) {
        float4 o = *(float4*)(orow + u * 4);
        o.x += sg * h[u*4+0]; o.y += sg * h[u*4+1];
        o.z += sg * h[u*4+2]; o.w += sg * h[u*4+3];
        *(float4*)(orow + u * 4) = o;
    }
}

extern "C" void kernel_launch(void* const* d_in, const int* in_sizes, int n_in,
                              void* d_out, int out_size, void* d_ws, size_t ws_size,
                              hipStream_t stream) {
    const float* x  = (const float*)d_in[0];
    const int* eidx = (const int*)d_in[1];
    const float* W1 = (const float*)d_in[2];
    const float* b1 = (const float*)d_in[3];
    const float* W2 = (const float*)d_in[4];
    const float* b2 = (const float*)d_in[5];
    const float* pw = (const float*)d_in[6];
    const float* pb = (const float*)d_in[7];
    float* out = (float*)d_out;

    const int N = in_sizes[0] / 256;
    const int E = in_sizes[1] / 2;
    const int NB = (N + 255) >> 8;              // dest buckets of 256
    const int NBK = NB * NR;                    // (bucket, range) keys
    const int M2 = NBK * NBLK;                  // count entries
    const int EPB = (E + NBLK - 1) / NBLK;      // edges per passA/passB block

    size_t woff = 0;
    auto alloc = [&](size_t bytes) -> void* {
        void* p = (char*)d_ws + woff;
        woff += (bytes + 255) & ~(size_t)255;
        return p;
    };
    int*   sflag   = (int*)alloc(4);
    float* dinv    = (float*)alloc((size_t)N * 4);
    int*   bsums   = (int*)alloc(1024 * 4);
    int*   pbase   = (int*)alloc(((size_t)M2 + 1) * 4);
    unsigned* seg  = (unsigned*)alloc((size_t)E * 4);
    unsigned short* W1f = (unsigned short*)alloc((size_t)256 * 256 * 2);
    unsigned short* W2f = (unsigned short*)alloc((size_t)64 * 256 * 2);
    unsigned short* gA = (unsigned short*)alloc((size_t)N * 64 * 2);
    unsigned short* gB = (unsigned short*)alloc((size_t)N * 64 * 2);

    detect_kernel<<<1, 256, 0, stream>>>((const unsigned*)eidx, sflag);

    // build: transposed histogram -> scan -> direct final scatter -> degree
    passA_kernel<<<NBLK, 256, 0, stream>>>(eidx, sflag, pbase, E, NBK, EPB);
    int nb2 = (M2 + 1023) / 1024;
    scan1_kernel<<<nb2, 256, 0, stream>>>(pbase, pbase, bsums, M2);
    scan2g_kernel<<<1, 256, 0, stream>>>(bsums, nb2);
    scan3_kernel<<<nb2, 256, 0, stream>>>(pbase, bsums, M2, E);
    passB_kernel<<<NBLK, 256, 0, stream>>>(eidx, sflag, pbase, seg, E, NBK, EPB);
    passD_kernel<<<NB, 256, 0, stream>>>(seg, pbase, dinv, N);

    // MLP (fused) + hop0
    wconv_kernel<<<(256 * 256 + 255) / 256, 256, 0, stream>>>(W1, W1f, 256, 256);
    wconv_kernel<<<(64 * 256 + 255) / 256, 256, 0, stream>>>(W2, W2f, 256, 64);
    int gb = (N + 63) / 64;
    mlp_fused<<<gb, 256, 0, stream>>>(x, W1f, b1, W2f, b2, dinv, pw, pb,
                                      out, gA, N);

    // propagation + fused pooling: bucket-LDS range-swept spmm
    unsigned short* gin = gA;
    unsigned short* gout = gB;
    for (int k = 0; k < 10; ++k) {
        spmm3_kernel<<<NB, 512, 0, stream>>>(pbase, seg, dinv,
                                             (const unsigned*)gin, (unsigned*)gout,
                                             out, pw, pb, N);
        unsigned short* t = gin; gin = gout; gout = t;
    }
}

// Round 5
// 2427.766 us; speedup vs baseline: 5.6890x; 5.6890x over previous
//
#include <hip/hip_runtime.h>
#include <hip/hip_bf16.h>
#include <math.h>

// DAGNN r14b (r14 with nontemporal-store compile fix):
//  - spmm4: channel-plane split for per-XCD L2 residency. State stored as
//    4 planes of 16 channels (3.2 MB bf16/plane); plane p pinned to XCD pair
//    {2p,2p+1} via blockIdx%8. Gathers hit an L2-resident buffer regardless
//    of access order -- keeps r11's proven per-dest full-window register
//    accumulation (r12/r13 lesson: never fragment windows / never LDS-atomic).
//  - plane-coupled pooling: per-plane partial dots dpart[c][4]; hop k applies
//    hop k-1's out += sg*h_prev (h_prev = gin*sdeg, already read as self-loop);
//    final kernel applies hop 10.
//  - streams (src, gout) nontemporal to protect L2 residency.
//  - build = r11's verified passes; dinv kernel also emits sdeg.

#define WAVE 64
#define NBLK 1024   // blocks in passA/passB; must match between them
#define RS 520      // LDS region stride in ushorts (64*8 + 8 pad)
#define DPW 16      // dests per wave in spmm4

__device__ inline float bf2f(unsigned short u) {
    union { unsigned int i; float f; } v; v.i = ((unsigned int)u) << 16; return v.f;
}
__device__ inline unsigned short f2bf(float f) {
    __hip_bfloat16 b = __float2bfloat16(f);
    union { __hip_bfloat16 b; unsigned short u; } v; v.b = b; return v.u;
}
__device__ inline float bflo(unsigned u) {
    union { unsigned i; float f; } v; v.i = u << 16; return v.f;
}
__device__ inline float bfhi(unsigned u) {
    union { unsigned i; float f; } v; v.i = u & 0xffff0000u; return v.f;
}

typedef __attribute__((ext_vector_type(8))) short bf16x8;
typedef __attribute__((ext_vector_type(16))) float f32x16;

// ---- edge dtype detection: stride 1 (int32) or 2 (int64 low words) ----
__global__ void detect_kernel(const unsigned* __restrict__ e, int* __restrict__ sflag) {
    __shared__ int any;
    if (threadIdx.x == 0) any = 0;
    __syncthreads();
    unsigned nz = 0;
    int t = threadIdx.x;
    for (int i = 0; i < 8; ++i) nz |= e[(size_t)(t * 8 + i) * 2 + 1];
    if (nz) atomicOr(&any, 1);
    __syncthreads();
    if (t == 0) *sflag = any ? 1 : 2;
}

// ---- passA: per-block LDS bucket histogram; blk_cnt[blk][bucket] ----
__global__ void passA_kernel(const int* __restrict__ eidx, const int* __restrict__ sflag,
                             int* __restrict__ blk_cnt, int E, int NB, int EPB) {
    __shared__ int lh[512];
    int t = threadIdx.x, blk = blockIdx.x;
    for (int i = t; i < NB; i += 256) lh[i] = 0;
    __syncthreads();
    int s = *sflag;
    int base = blk * EPB;
    int end = base + EPB; if (end > E) end = E;
    for (int e = base + t; e < end; e += 256) {
        int c = eidx[(size_t)s * (size_t)(E + e)];
        atomicAdd(&lh[c >> 8], 1);
    }
    __syncthreads();
    for (int i = t; i < NB; i += 256)
        blk_cnt[(size_t)blk * NB + i] = lh[i];
}

// ---- scans ----
__global__ void scan1_kernel(const int* __restrict__ in, int* __restrict__ out,
                             int* __restrict__ bsums, int n) {
    __shared__ int s[256];
    int t = threadIdx.x;
    int idx = blockIdx.x * 1024 + t * 4;
    int x0 = (idx + 0 < n) ? in[idx + 0] : 0;
    int x1 = (idx + 1 < n) ? in[idx + 1] : 0;
    int x2 = (idx + 2 < n) ? in[idx + 2] : 0;
    int x3 = (idx + 3 < n) ? in[idx + 3] : 0;
    int lsum = x0 + x1 + x2 + x3;
    s[t] = lsum;
    __syncthreads();
    for (int o = 1; o < 256; o <<= 1) {
        int v = (t >= o) ? s[t - o] : 0;
        __syncthreads();
        if (t >= o) s[t] += v;
        __syncthreads();
    }
    int excl = s[t] - lsum;
    if (idx + 0 < n) out[idx + 0] = excl;
    if (idx + 1 < n) out[idx + 1] = excl + x0;
    if (idx + 2 < n) out[idx + 2] = excl + x0 + x1;
    if (idx + 3 < n) out[idx + 3] = excl + x0 + x1 + x2;
    if (t == 255) bsums[blockIdx.x] = s[255];
}

__global__ void scan2g_kernel(int* __restrict__ bsums, int nb) {
    __shared__ int part[256];
    int t = threadIdx.x;
    int v[4]; int run = 0;
    #pragma unroll
    for (int j = 0; j < 4; ++j) {
        int i = t * 4 + j;
        int x = (i < nb) ? bsums[i] : 0;
        v[j] = run; run += x;
    }
    part[t] = run;
    __syncthreads();
    for (int o = 1; o < 256; o <<= 1) {
        int x = (t >= o) ? part[t - o] : 0;
        __syncthreads();
        if (t >= o) part[t] += x;
        __syncthreads();
    }
    int excl = part[t] - run;
    #pragma unroll
    for (int j = 0; j < 4; ++j) {
        int i = t * 4 + j;
        if (i < nb) bsums[i] = excl + v[j];
    }
}

__global__ void scan3_kernel(int* __restrict__ arr, const int* __restrict__ bsums,
                             int n, int total) {
    int t = threadIdx.x;
    int idx = blockIdx.x * 1024 + t * 4;
    int add = bsums[blockIdx.x];
    #pragma unroll
    for (int i = 0; i < 4; ++i)
        if (idx + i < n) arr[idx + i] += add;
    if (blockIdx.x == 0 && t == 0) arr[n] = total;
}

// ---- passB: LDS-cursor pair scatter; windows block-major (dense per block) ----
__global__ void passB_kernel(const int* __restrict__ eidx, const int* __restrict__ sflag,
                             const int* __restrict__ pbase, int2* __restrict__ pairs,
                             int E, int NB, int EPB) {
    __shared__ int lcur[512];
    int t = threadIdx.x, blk = blockIdx.x;
    for (int i = t; i < NB; i += 256) lcur[i] = pbase[(size_t)blk * NB + i];
    __syncthreads();
    int s = *sflag;
    int base = blk * EPB;
    int end = base + EPB; if (end > E) end = E;
    for (int e = base + t; e < end; e += 256) {
        int r = eidx[(size_t)s * (size_t)e];
        int c = eidx[(size_t)s * (size_t)(E + e)];
        int pos = atomicAdd(&lcur[c >> 8], 1);
        pairs[pos] = make_int2(r, c);
    }
}

// ---- passD: per-bucket node degree counts; windows at pbase[blk*NB+b] ----
__global__ void passD_kernel(const int2* __restrict__ pairs, const int* __restrict__ pbase,
                             int* __restrict__ cnt, int N, int NB) {
    __shared__ int lcnt[256];
    int b = blockIdx.x, t = threadIdx.x;
    lcnt[t] = 0;
    __syncthreads();
    for (int blk = t; blk < NBLK; blk += 256) {
        int w0 = pbase[(size_t)blk * NB + b];
        int w1 = pbase[(size_t)blk * NB + b + 1];
        for (int i = w0; i < w1; ++i)
            atomicAdd(&lcnt[pairs[i].y & 255], 1);
    }
    __syncthreads();
    int node = b * 256 + t;
    if (node < N) cnt[node] = lcnt[t];
}

__global__ void dinv_kernel(const int* __restrict__ cnt, float* __restrict__ dinv,
                            float* __restrict__ sdeg, int n) {
    int i = blockIdx.x * blockDim.x + threadIdx.x;
    if (i < n) {
        float d1 = (float)(cnt[i] + 1);      // self-loop adds 1
        dinv[i] = rsqrtf(d1);
        sdeg[i] = sqrtf(d1);
    }
}

// ---- passC: per-bucket LDS cursors, scatter src into final CSR window ----
__global__ void passC_kernel(const int2* __restrict__ pairs, const int* __restrict__ pbase,
                             const int* __restrict__ offs, int* __restrict__ csr_src,
                             int N, int NB) {
    __shared__ int lcur[256];
    int b = blockIdx.x, t = threadIdx.x;
    int node = b * 256 + t;
    lcur[t] = (node < N) ? offs[node] : 0;
    __syncthreads();
    for (int blk = t; blk < NBLK; blk += 256) {
        int w0 = pbase[(size_t)blk * NB + b];
        int w1 = pbase[(size_t)blk * NB + b + 1];
        for (int i = w0; i < w1; ++i) {
            int2 p = pairs[i];
            int pos = atomicAdd(&lcur[p.y & 255], 1);
            csr_src[pos] = p.x;
        }
    }
}

// ---- weight convert to fragment-major: Wf[(k>>3)*Nn*8 + n*8 + (k&7)] = bf16(W[k][n]) ----
__global__ void wconv_kernel(const float* __restrict__ W, unsigned short* __restrict__ Wf,
                             int K, int Nn) {
    int i = blockIdx.x * blockDim.x + threadIdx.x;
    if (i >= K * Nn) return;
    int k = i / Nn, n = i - k * Nn;
    Wf[(size_t)(k >> 3) * Nn * 8 + n * 8 + (k & 7)] = f2bf(W[i]);
}

// ---- fused MLP: h = relu(x@W1+b1)@W2+b2 ; out = sigmoid(h.pw+pb)*h ;
//      g0 = bf16(dinv*h) written in 4x16-channel PLANE layout. ----
__global__ __launch_bounds__(256, 4) void mlp_fused(
        const float* __restrict__ x,
        const unsigned short* __restrict__ W1f,   // frag-major [k>>3][256 n][8]
        const float* __restrict__ b1,
        const unsigned short* __restrict__ W2f,   // frag-major [k>>3][64 n][8]
        const float* __restrict__ b2,
        const float* __restrict__ dinv,
        const float* __restrict__ pw, const float* __restrict__ pb,
        float* __restrict__ out, unsigned short* __restrict__ g,
        int M) {
    __shared__ unsigned short xfrag[4 * RS];    // region = (k&31)>>3
    __shared__ unsigned short h1frag[32 * RS];  // region = ch>>3 (stage-2 k)
    __shared__ float pools[2][2][2][16];        // [rt2][ct2][half][reg]

    int tid = threadIdx.x;
    int wave = tid >> 6, lane = tid & 63;
    int half = lane >> 5, l31 = lane & 31;
    int rt = wave & 1;          // stage-1 row tile (32 rows)
    int cw = wave >> 1;         // stage-1 col half (128 cols)
    int bm = blockIdx.x * 64;

    f32x16 acc1[4] = {};

    float4 xv[2];
    #pragma unroll
    for (int i = 0; i < 2; ++i) {
        int f = i * 256 + tid;
        int row = f >> 3, c4 = (f & 7) * 4;
        int grow = bm + row;
        xv[i] = (grow < M) ? *(const float4*)(x + (size_t)grow * 256 + c4)
                           : make_float4(0.f, 0.f, 0.f, 0.f);
    }

    for (int it = 0; it < 8; ++it) {
        #pragma unroll
        for (int i = 0; i < 2; ++i) {
            int f = i * 256 + tid;
            int row = f >> 3, c4 = (f & 7) * 4;
            int region = c4 >> 3, off = c4 & 7;
            ushort4 u;
            u.x = f2bf(xv[i].x); u.y = f2bf(xv[i].y);
            u.z = f2bf(xv[i].z); u.w = f2bf(xv[i].w);
            *(ushort4*)&xfrag[region * RS + row * 8 + off] = u;
        }
        __syncthreads();
        if (it < 7) {
            int k0 = (it + 1) * 32;
            #pragma unroll
            for (int i = 0; i < 2; ++i) {
                int f = i * 256 + tid;
                int row = f >> 3, c4 = (f & 7) * 4;
                int grow = bm + row;
                xv[i] = (grow < M) ? *(const float4*)(x + (size_t)grow * 256 + k0 + c4)
                                   : make_float4(0.f, 0.f, 0.f, 0.f);
            }
        }
        #pragma unroll
        for (int s = 0; s < 2; ++s) {
            int region = it * 4 + s * 2 + half;          // k>>3 of this fragment
            bf16x8 a = *(bf16x8*)&xfrag[(s * 2 + half) * RS + (rt * 32 + l31) * 8];
            #pragma unroll
            for (int j = 0; j < 4; ++j) {
                int ch = cw * 128 + j * 32 + l31;
                bf16x8 b = *(const bf16x8*)(W1f + (size_t)region * 2048 + ch * 8);
                acc1[j] = __builtin_amdgcn_mfma_f32_32x32x16_bf16(a, b, acc1[j], 0, 0, 0);
            }
        }
        __syncthreads();
    }

    // bias + relu, write h1 tile to LDS in stage-2 A-fragment layout
    #pragma unroll
    for (int j = 0; j < 4; ++j) {
        int ch = cw * 128 + j * 32 + l31;     // stage-2 k index
        float bb = b1[ch];
        int region = ch >> 3, off = ch & 7;
        #pragma unroll
        for (int reg = 0; reg < 16; ++reg) {
            int rowin = (reg & 3) + 8 * (reg >> 2) + 4 * half;
            int row = rt * 32 + rowin;
            float v = fmaxf(acc1[j][reg] + bb, 0.f);
            h1frag[region * RS + row * 8 + off] = f2bf(v);
        }
    }
    __syncthreads();

    // stage 2 on all 4 waves: wave = rt2*2 + ct2 tile (32 rows x 32 cols)
    int rt2 = wave >> 1, ct2 = wave & 1;
    f32x16 acc2 = {};
    #pragma unroll
    for (int s = 0; s < 16; ++s) {
        bf16x8 a = *(bf16x8*)&h1frag[(s * 2 + half) * RS + (rt2 * 32 + l31) * 8];
        bf16x8 b = *(const bf16x8*)(W2f + (size_t)(s * 2 + half) * 512 + (ct2 * 32 + l31) * 8);
        acc2 = __builtin_amdgcn_mfma_f32_32x32x16_bf16(a, b, acc2, 0, 0, 0);
    }

    float bb = b2[ct2 * 32 + l31];
    float pwv = pw[ct2 * 32 + l31];
    float pbv = pb[0];
    float hreg[16];
    #pragma unroll
    for (int reg = 0; reg < 16; ++reg) {
        float h = acc2[reg] + bb;
        hreg[reg] = h;
        float d = h * pwv;
        d += __shfl_xor(d, 1, 64);
        d += __shfl_xor(d, 2, 64);
        d += __shfl_xor(d, 4, 64);
        d += __shfl_xor(d, 8, 64);
        d += __shfl_xor(d, 16, 64);
        if (l31 == 0) pools[rt2][ct2][half][reg] = d;
    }
    __syncthreads();
    int ch = ct2 * 32 + l31;
    #pragma unroll
    for (int reg = 0; reg < 16; ++reg) {
        int rowin = (reg & 3) + 8 * (reg >> 2) + 4 * half;
        int row = bm + rt2 * 32 + rowin;
        float d = pools[rt2][0][half][reg] + pools[rt2][1][half][reg];
        float sg = 1.f / (1.f + __expf(-(d + pbv)));
        float h = hreg[reg];
        if (row < M) {
            float dv = dinv[row];
            out[(size_t)row * 64 + ch] = sg * h;
            // plane layout: plane = ch>>4, in-plane channel = ch&15
            g[((size_t)(ch >> 4) * (size_t)M + (size_t)row) * 16 + (ch & 15)]
                = f2bf(dv * h);
        }
    }
}

// ---- one hop (r14): plane-per-XCD-pair gather. Wave sweeps DPW dests;
//      16 edge slots x 4 lanes (uint2 = 4 ch), 2 slot-rounds in flight.
//      Fused: dpart partial dot + prev-hop out update (uses self-loop read). ----
__global__ __launch_bounds__(256) void spmm4_kernel(
        const int* __restrict__ offs, const int* __restrict__ src,
        const float* __restrict__ dinv, const float* __restrict__ sdeg,
        const unsigned* __restrict__ gin,   // 4 planes [p][n][8 dwords]
        unsigned* __restrict__ gout,
        const float* __restrict__ dpin, float* __restrict__ dpout,
        float* __restrict__ out,
        const float* __restrict__ pw, const float* __restrict__ pb,
        int n, int do_prev) {
    int lane = threadIdx.x & 63;
    int wv = threadIdx.x >> 6;
    int blk = blockIdx.x;
    int plane = (blk & 7) >> 1;     // XCD pair {2p,2p+1} handles plane p
    int sub = blk & 1;
    int pblk = blk >> 3;
    int base = (((pblk << 1) | sub) * 4 + wv) * DPW;
    if (base >= n) return;
    int sl = (lane >> 2) & 15;      // edge slot 0..15
    int q = lane & 3;               // channel quad: dwords 2q,2q+1
    const unsigned* gpl = gin + (size_t)plane * (size_t)n * 8;
    unsigned* gopl = gout + (size_t)plane * (size_t)n * 8;
    float pbv = pb[0];
    float4 pv = *(const float4*)(pw + plane * 16 + q * 4);

    for (int j = 0; j < DPW; ++j) {
        int c = base + j;
        if (c >= n) break;
        int e0 = __builtin_amdgcn_readfirstlane(offs[c]);
        int e1 = __builtin_amdgcn_readfirstlane(offs[c + 1]);
        float a0 = 0.f, a1 = 0.f, a2 = 0.f, a3 = 0.f;
        for (int e = e0; e < e1; e += 32) {
            int ei0 = e + sl, ei1 = e + 16 + sl;
            int ec0 = ei0 < e1 ? ei0 : e1 - 1;
            int ec1 = ei1 < e1 ? ei1 : e1 - 1;
            unsigned m0 = ei0 < e1 ? 0xffffffffu : 0u;
            unsigned m1 = ei1 < e1 ? 0xffffffffu : 0u;
            int s0 = __builtin_nontemporal_load(src + ec0);
            int s1 = __builtin_nontemporal_load(src + ec1);
            uint2 v0 = *(const uint2*)(gpl + (size_t)s0 * 8 + q * 2);
            uint2 v1 = *(const uint2*)(gpl + (size_t)s1 * 8 + q * 2);
            v0.x &= m0; v0.y &= m0; v1.x &= m1; v1.y &= m1;
            a0 += bflo(v0.x) + bflo(v1.x);
            a1 += bfhi(v0.x) + bfhi(v1.x);
            a2 += bflo(v0.y) + bflo(v1.y);
            a3 += bfhi(v0.y) + bfhi(v1.y);
        }
        // reduce across the 16 edge slots (lane bits 2..5)
        a0 += __shfl_xor(a0, 4, 64); a0 += __shfl_xor(a0, 8, 64);
        a0 += __shfl_xor(a0, 16, 64); a0 += __shfl_xor(a0, 32, 64);
        a1 += __shfl_xor(a1, 4, 64); a1 += __shfl_xor(a1, 8, 64);
        a1 += __shfl_xor(a1, 16, 64); a1 += __shfl_xor(a1, 32, 64);
        a2 += __shfl_xor(a2, 4, 64); a2 += __shfl_xor(a2, 8, 64);
        a2 += __shfl_xor(a2, 16, 64); a2 += __shfl_xor(a2, 32, 64);
        a3 += __shfl_xor(a3, 4, 64); a3 += __shfl_xor(a3, 8, 64);
        a3 += __shfl_xor(a3, 16, 64); a3 += __shfl_xor(a3, 32, 64);

        uint2 sv = *(const uint2*)(gpl + (size_t)c * 8 + q * 2);  // self-loop
        float f0 = bflo(sv.x), f1 = bfhi(sv.x);
        float f2v = bflo(sv.y), f3 = bfhi(sv.y);
        float dc = dinv[c];
        float h0 = dc * (a0 + f0), h1 = dc * (a1 + f1);
        float h2 = dc * (a2 + f2v), h3 = dc * (a3 + f3);

        // plane-partial pooling dot
        float d = h0 * pv.x + h1 * pv.y + h2 * pv.z + h3 * pv.w;
        d += __shfl_xor(d, 1, 64);
        d += __shfl_xor(d, 2, 64);
        if (lane == 0) dpout[(size_t)c * 4 + plane] = d;

        if (lane < 4) {   // q = lane, slot 0: owns the 16 plane channels
            unsigned gw0 = (unsigned)f2bf(dc * h0) | ((unsigned)f2bf(dc * h1) << 16);
            unsigned gw1 = (unsigned)f2bf(dc * h2) | ((unsigned)f2bf(dc * h3) << 16);
            unsigned* gp = gopl + (size_t)c * 8 + lane * 2;
            __builtin_nontemporal_store(gw0, gp);
            __builtin_nontemporal_store(gw1, gp + 1);
            if (do_prev) {
                float4 dp = *(const float4*)(dpin + (size_t)c * 4);
                float sg = 1.f / (1.f + __expf(-(dp.x + dp.y + dp.z + dp.w + pbv)));
                float sd = sdeg[c] * sg;     // h_prev = gin * sdeg
                float* op = out + (size_t)c * 64 + plane * 16 + lane * 4;
                float4 o = *(float4*)op;
                o.x += sd * f0; o.y += sd * f1;
                o.z += sd * f2v; o.w += sd * f3;
                *(float4*)op = o;
            }
        }
    }
}

// ---- final: apply hop-10's out contribution ----
__global__ void final_kernel(const unsigned* __restrict__ glast,
                             const float* __restrict__ dplast,
                             const float* __restrict__ sdeg,
                             const float* __restrict__ pb,
                             float* __restrict__ out, int n) {
    int tid = blockIdx.x * 256 + threadIdx.x;
    int c = tid >> 4;
    if (c >= n) return;
    int w = tid & 15;               // channels w*4 .. w*4+3
    int plane = w >> 2, q = w & 3;
    float4 dp = *(const float4*)(dplast + (size_t)c * 4);
    float sg = 1.f / (1.f + __expf(-(dp.x + dp.y + dp.z + dp.w + pb[0])));
    float sd = sdeg[c] * sg;
    uint2 v = *(const uint2*)(glast + ((size_t)plane * n + c) * 8 + q * 2);
    float4 o = *(float4*)(out + (size_t)c * 64 + w * 4);
    o.x += sd * bflo(v.x); o.y += sd * bfhi(v.x);
    o.z += sd * bflo(v.y); o.w += sd * bfhi(v.y);
    *(float4*)(out + (size_t)c * 64 + w * 4) = o;
}

extern "C" void kernel_launch(void* const* d_in, const int* in_sizes, int n_in,
                              void* d_out, int out_size, void* d_ws, size_t ws_size,
                              hipStream_t stream) {
    const float* x  = (const float*)d_in[0];
    const int* eidx = (const int*)d_in[1];
    const float* W1 = (const float*)d_in[2];
    const float* b1 = (const float*)d_in[3];
    const float* W2 = (const float*)d_in[4];
    const float* b2 = (const float*)d_in[5];
    const float* pw = (const float*)d_in[6];
    const float* pb = (const float*)d_in[7];
    float* out = (float*)d_out;

    const int N = in_sizes[0] / 256;
    const int E = in_sizes[1] / 2;
    const int NB = (N + 255) >> 8;              // buckets of 256 dest nodes
    const int EPB = (E + NBLK - 1) / NBLK;      // edges per passA/passB block
    const int M = NB * NBLK;                    // blk_cnt entries

    size_t woff = 0;
    auto alloc = [&](size_t bytes) -> void* {
        void* p = (char*)d_ws + woff;
        woff += (bytes + 255) & ~(size_t)255;
        return p;
    };
    int*   sflag   = (int*)alloc(4);
    int*   cnt     = (int*)alloc((size_t)N * 4);
    float* dinv    = (float*)alloc((size_t)N * 4);
    float* sdeg    = (float*)alloc((size_t)N * 4);
    int*   offs    = (int*)alloc(((size_t)N + 1) * 4);
    int*   bsums   = (int*)alloc(1024 * 4);
    int*   bsums2  = (int*)alloc(1024 * 4);
    int*   pbase   = (int*)alloc(((size_t)M + 1) * 4);
    int*   csr_src = (int*)alloc((size_t)E * 4);
    int2*  pairs   = (int2*)alloc((size_t)E * 8);
    unsigned short* W1f = (unsigned short*)alloc((size_t)256 * 256 * 2);
    unsigned short* W2f = (unsigned short*)alloc((size_t)64 * 256 * 2);
    unsigned short* gA = (unsigned short*)alloc((size_t)N * 64 * 2);
    unsigned short* gB = (unsigned short*)alloc((size_t)N * 64 * 2);
    float* dpA = (float*)alloc((size_t)N * 16);
    float* dpB = (float*)alloc((size_t)N * 16);

    detect_kernel<<<1, 256, 0, stream>>>((const unsigned*)eidx, sflag);

    // build: histogram -> scan -> pair scatter -> node counts -> offs -> CSR
    passA_kernel<<<NBLK, 256, 0, stream>>>(eidx, sflag, pbase, E, NB, EPB);
    int nb2 = (M + 1023) / 1024;
    scan1_kernel<<<nb2, 256, 0, stream>>>(pbase, pbase, bsums2, M);
    scan2g_kernel<<<1, 256, 0, stream>>>(bsums2, nb2);
    scan3_kernel<<<nb2, 256, 0, stream>>>(pbase, bsums2, M, E);
    passB_kernel<<<NBLK, 256, 0, stream>>>(eidx, sflag, pbase, pairs, E, NB, EPB);
    passD_kernel<<<NB, 256, 0, stream>>>(pairs, pbase, cnt, N, NB);
    dinv_kernel<<<(N + 255) / 256, 256, 0, stream>>>(cnt, dinv, sdeg, N);
    int nb1 = (N + 1023) / 1024;
    scan1_kernel<<<nb1, 256, 0, stream>>>(cnt, offs, bsums, N);
    scan2g_kernel<<<1, 256, 0, stream>>>(bsums, nb1);
    scan3_kernel<<<nb1, 256, 0, stream>>>(offs, bsums, N, E);
    passC_kernel<<<NB, 256, 0, stream>>>(pairs, pbase, offs, csr_src, N, NB);

    // MLP (fused) + hop0 (writes out = sg0*h0, gA planes = dinv*h0)
    wconv_kernel<<<(256 * 256 + 255) / 256, 256, 0, stream>>>(W1, W1f, 256, 256);
    wconv_kernel<<<(64 * 256 + 255) / 256, 256, 0, stream>>>(W2, W2f, 256, 64);
    int gb = (N + 63) / 64;
    mlp_fused<<<gb, 256, 0, stream>>>(x, W1f, b1, W2f, b2, dinv, pw, pb,
                                      out, gA, N);

    // propagation: plane-resident gather; hop k applies hop k-1's out update
    int bpx2 = (N + 8 * DPW - 1) / (8 * DPW);
    int grid4 = 8 * bpx2;
    unsigned short* gin = gA;
    unsigned short* gout = gB;
    float* dpin = dpA;
    float* dpout = dpB;
    for (int k = 0; k < 10; ++k) {
        spmm4_kernel<<<grid4, 256, 0, stream>>>(offs, csr_src, dinv, sdeg,
                                                (const unsigned*)gin, (unsigned*)gout,
                                                dpin, dpout, out, pw, pb, N, k > 0);
        unsigned short* t = gin; gin = gout; gout = t;
        float* td = dpin; dpin = dpout; dpout = td;
    }
    // apply hop-10 contribution (gin/dpin hold the last hop's outputs)
    final_kernel<<<(N * 16 + 255) / 256, 256, 0, stream>>>(
        (const unsigned*)gin, dpin, sdeg, pb, out, N);
}

// Round 6
// 1004.397 us; speedup vs baseline: 13.7511x; 2.4171x over previous
//
#include <hip/hip_runtime.h>
#include <hip/hip_bf16.h>
#include <math.h>

// DAGNN r15:
//  - spmm5: pure gather hop (r11's proven per-dest structure). 8 lanes/row
//    dwordx4 gather (8 edges per instruction, 16 in flight), register accs.
//    NO fused out-RMW / pooling (removes 51MB/hop stream + epilogue VALU).
//    Hop k reads preds plane k-1, writes plane k (11-plane chain, no pingpong).
//  - pool_kernel: one final streaming pass over all 11 planes computes
//    out = sum_k sigmoid(h_k . pw + pb) * h_k   (h_k = sdeg * g_k).
//  - mlp_fused sheds its out write + pooling code; writes plane 0 only.
//  - build: r11's verified passes; pairs overlaid on preds planes 1-2
//    (dead after passC, plane1 first written by hop 1).
//  - r12/r13/r14 lessons: no src-range fragmentation, no LDS atomics,
//    no channel-plane split (4x index stream + 4x VALU + line overfetch).

#define WAVE 64
#define NBLK 1024   // blocks in passA/passB; must match between them
#define RS 520      // LDS region stride in ushorts (64*8 + 8 pad)

__device__ inline float bf2f(unsigned short u) {
    union { unsigned int i; float f; } v; v.i = ((unsigned int)u) << 16; return v.f;
}
__device__ inline unsigned short f2bf(float f) {
    __hip_bfloat16 b = __float2bfloat16(f);
    union { __hip_bfloat16 b; unsigned short u; } v; v.b = b; return v.u;
}
__device__ inline float bflo(unsigned u) {
    union { unsigned i; float f; } v; v.i = u << 16; return v.f;
}
__device__ inline float bfhi(unsigned u) {
    union { unsigned i; float f; } v; v.i = u & 0xffff0000u; return v.f;
}

typedef __attribute__((ext_vector_type(8))) short bf16x8;
typedef __attribute__((ext_vector_type(16))) float f32x16;

// ---- edge dtype detection: stride 1 (int32) or 2 (int64 low words) ----
__global__ void detect_kernel(const unsigned* __restrict__ e, int* __restrict__ sflag) {
    __shared__ int any;
    if (threadIdx.x == 0) any = 0;
    __syncthreads();
    unsigned nz = 0;
    int t = threadIdx.x;
    for (int i = 0; i < 8; ++i) nz |= e[(size_t)(t * 8 + i) * 2 + 1];
    if (nz) atomicOr(&any, 1);
    __syncthreads();
    if (t == 0) *sflag = any ? 1 : 2;
}

// ---- passA: per-block LDS bucket histogram; blk_cnt[blk][bucket] ----
__global__ void passA_kernel(const int* __restrict__ eidx, const int* __restrict__ sflag,
                             int* __restrict__ blk_cnt, int E, int NB, int EPB) {
    __shared__ int lh[512];
    int t = threadIdx.x, blk = blockIdx.x;
    for (int i = t; i < NB; i += 256) lh[i] = 0;
    __syncthreads();
    int s = *sflag;
    int base = blk * EPB;
    int end = base + EPB; if (end > E) end = E;
    for (int e = base + t; e < end; e += 256) {
        int c = eidx[(size_t)s * (size_t)(E + e)];
        atomicAdd(&lh[c >> 8], 1);
    }
    __syncthreads();
    for (int i = t; i < NB; i += 256)
        blk_cnt[(size_t)blk * NB + i] = lh[i];
}

// ---- scans ----
__global__ void scan1_kernel(const int* __restrict__ in, int* __restrict__ out,
                             int* __restrict__ bsums, int n) {
    __shared__ int s[256];
    int t = threadIdx.x;
    int idx = blockIdx.x * 1024 + t * 4;
    int x0 = (idx + 0 < n) ? in[idx + 0] : 0;
    int x1 = (idx + 1 < n) ? in[idx + 1] : 0;
    int x2 = (idx + 2 < n) ? in[idx + 2] : 0;
    int x3 = (idx + 3 < n) ? in[idx + 3] : 0;
    int lsum = x0 + x1 + x2 + x3;
    s[t] = lsum;
    __syncthreads();
    for (int o = 1; o < 256; o <<= 1) {
        int v = (t >= o) ? s[t - o] : 0;
        __syncthreads();
        if (t >= o) s[t] += v;
        __syncthreads();
    }
    int excl = s[t] - lsum;
    if (idx + 0 < n) out[idx + 0] = excl;
    if (idx + 1 < n) out[idx + 1] = excl + x0;
    if (idx + 2 < n) out[idx + 2] = excl + x0 + x1;
    if (idx + 3 < n) out[idx + 3] = excl + x0 + x1 + x2;
    if (t == 255) bsums[blockIdx.x] = s[255];
}

__global__ void scan2g_kernel(int* __restrict__ bsums, int nb) {
    __shared__ int part[256];
    int t = threadIdx.x;
    int v[4]; int run = 0;
    #pragma unroll
    for (int j = 0; j < 4; ++j) {
        int i = t * 4 + j;
        int x = (i < nb) ? bsums[i] : 0;
        v[j] = run; run += x;
    }
    part[t] = run;
    __syncthreads();
    for (int o = 1; o < 256; o <<= 1) {
        int x = (t >= o) ? part[t - o] : 0;
        __syncthreads();
        if (t >= o) part[t] += x;
        __syncthreads();
    }
    int excl = part[t] - run;
    #pragma unroll
    for (int j = 0; j < 4; ++j) {
        int i = t * 4 + j;
        if (i < nb) bsums[i] = excl + v[j];
    }
}

__global__ void scan3_kernel(int* __restrict__ arr, const int* __restrict__ bsums,
                             int n, int total) {
    int t = threadIdx.x;
    int idx = blockIdx.x * 1024 + t * 4;
    int add = bsums[blockIdx.x];
    #pragma unroll
    for (int i = 0; i < 4; ++i)
        if (idx + i < n) arr[idx + i] += add;
    if (blockIdx.x == 0 && t == 0) arr[n] = total;
}

// ---- passB: LDS-cursor pair scatter; windows block-major (dense per block) ----
__global__ void passB_kernel(const int* __restrict__ eidx, const int* __restrict__ sflag,
                             const int* __restrict__ pbase, int2* __restrict__ pairs,
                             int E, int NB, int EPB) {
    __shared__ int lcur[512];
    int t = threadIdx.x, blk = blockIdx.x;
    for (int i = t; i < NB; i += 256) lcur[i] = pbase[(size_t)blk * NB + i];
    __syncthreads();
    int s = *sflag;
    int base = blk * EPB;
    int end = base + EPB; if (end > E) end = E;
    for (int e = base + t; e < end; e += 256) {
        int r = eidx[(size_t)s * (size_t)e];
        int c = eidx[(size_t)s * (size_t)(E + e)];
        int pos = atomicAdd(&lcur[c >> 8], 1);
        pairs[pos] = make_int2(r, c);
    }
}

// ---- passD: per-bucket node degree counts; windows at pbase[blk*NB+b] ----
__global__ void passD_kernel(const int2* __restrict__ pairs, const int* __restrict__ pbase,
                             int* __restrict__ cnt, int N, int NB) {
    __shared__ int lcnt[256];
    int b = blockIdx.x, t = threadIdx.x;
    lcnt[t] = 0;
    __syncthreads();
    for (int blk = t; blk < NBLK; blk += 256) {
        int w0 = pbase[(size_t)blk * NB + b];
        int w1 = pbase[(size_t)blk * NB + b + 1];
        for (int i = w0; i < w1; ++i)
            atomicAdd(&lcnt[pairs[i].y & 255], 1);
    }
    __syncthreads();
    int node = b * 256 + t;
    if (node < N) cnt[node] = lcnt[t];
}

__global__ void dinv_kernel(const int* __restrict__ cnt, float* __restrict__ dinv,
                            float* __restrict__ sdeg, int n) {
    int i = blockIdx.x * blockDim.x + threadIdx.x;
    if (i < n) {
        float d1 = (float)(cnt[i] + 1);      // self-loop adds 1
        dinv[i] = rsqrtf(d1);
        sdeg[i] = sqrtf(d1);
    }
}

// ---- passC: per-bucket LDS cursors, scatter src into final CSR window ----
__global__ void passC_kernel(const int2* __restrict__ pairs, const int* __restrict__ pbase,
                             const int* __restrict__ offs, int* __restrict__ csr_src,
                             int N, int NB) {
    __shared__ int lcur[256];
    int b = blockIdx.x, t = threadIdx.x;
    int node = b * 256 + t;
    lcur[t] = (node < N) ? offs[node] : 0;
    __syncthreads();
    for (int blk = t; blk < NBLK; blk += 256) {
        int w0 = pbase[(size_t)blk * NB + b];
        int w1 = pbase[(size_t)blk * NB + b + 1];
        for (int i = w0; i < w1; ++i) {
            int2 p = pairs[i];
            int pos = atomicAdd(&lcur[p.y & 255], 1);
            csr_src[pos] = p.x;
        }
    }
}

// ---- weight convert to fragment-major: Wf[(k>>3)*Nn*8 + n*8 + (k&7)] = bf16(W[k][n]) ----
__global__ void wconv_kernel(const float* __restrict__ W, unsigned short* __restrict__ Wf,
                             int K, int Nn) {
    int i = blockIdx.x * blockDim.x + threadIdx.x;
    if (i >= K * Nn) return;
    int k = i / Nn, n = i - k * Nn;
    Wf[(size_t)(k >> 3) * Nn * 8 + n * 8 + (k & 7)] = f2bf(W[i]);
}

// ---- fused MLP: h = relu(x@W1+b1)@W2+b2 ; g0 = bf16(dinv*h) (preds plane 0).
//      BM=64 rows/block, 256 thr (4 waves). Pooling deferred to pool_kernel. ----
__global__ __launch_bounds__(256, 4) void mlp_fused(
        const float* __restrict__ x,
        const unsigned short* __restrict__ W1f,   // frag-major [k>>3][256 n][8]
        const float* __restrict__ b1,
        const unsigned short* __restrict__ W2f,   // frag-major [k>>3][64 n][8]
        const float* __restrict__ b2,
        const float* __restrict__ dinv,
        unsigned short* __restrict__ g,
        int M) {
    __shared__ unsigned short xfrag[4 * RS];    // region = (k&31)>>3
    __shared__ unsigned short h1frag[32 * RS];  // region = ch>>3 (stage-2 k)

    int tid = threadIdx.x;
    int wave = tid >> 6, lane = tid & 63;
    int half = lane >> 5, l31 = lane & 31;
    int rt = wave & 1;          // stage-1 row tile (32 rows)
    int cw = wave >> 1;         // stage-1 col half (128 cols)
    int bm = blockIdx.x * 64;

    f32x16 acc1[4] = {};

    float4 xv[2];
    #pragma unroll
    for (int i = 0; i < 2; ++i) {
        int f = i * 256 + tid;
        int row = f >> 3, c4 = (f & 7) * 4;
        int grow = bm + row;
        xv[i] = (grow < M) ? *(const float4*)(x + (size_t)grow * 256 + c4)
                           : make_float4(0.f, 0.f, 0.f, 0.f);
    }

    for (int it = 0; it < 8; ++it) {
        #pragma unroll
        for (int i = 0; i < 2; ++i) {
            int f = i * 256 + tid;
            int row = f >> 3, c4 = (f & 7) * 4;
            int region = c4 >> 3, off = c4 & 7;
            ushort4 u;
            u.x = f2bf(xv[i].x); u.y = f2bf(xv[i].y);
            u.z = f2bf(xv[i].z); u.w = f2bf(xv[i].w);
            *(ushort4*)&xfrag[region * RS + row * 8 + off] = u;
        }
        __syncthreads();
        if (it < 7) {
            int k0 = (it + 1) * 32;
            #pragma unroll
            for (int i = 0; i < 2; ++i) {
                int f = i * 256 + tid;
                int row = f >> 3, c4 = (f & 7) * 4;
                int grow = bm + row;
                xv[i] = (grow < M) ? *(const float4*)(x + (size_t)grow * 256 + k0 + c4)
                                   : make_float4(0.f, 0.f, 0.f, 0.f);
            }
        }
        #pragma unroll
        for (int s = 0; s < 2; ++s) {
            int region = it * 4 + s * 2 + half;          // k>>3 of this fragment
            bf16x8 a = *(bf16x8*)&xfrag[(s * 2 + half) * RS + (rt * 32 + l31) * 8];
            #pragma unroll
            for (int j = 0; j < 4; ++j) {
                int ch = cw * 128 + j * 32 + l31;
                bf16x8 b = *(const bf16x8*)(W1f + (size_t)region * 2048 + ch * 8);
                acc1[j] = __builtin_amdgcn_mfma_f32_32x32x16_bf16(a, b, acc1[j], 0, 0, 0);
            }
        }
        __syncthreads();
    }

    // bias + relu, write h1 tile to LDS in stage-2 A-fragment layout
    #pragma unroll
    for (int j = 0; j < 4; ++j) {
        int ch = cw * 128 + j * 32 + l31;     // stage-2 k index
        float bb = b1[ch];
        int region = ch >> 3, off = ch & 7;
        #pragma unroll
        for (int reg = 0; reg < 16; ++reg) {
            int rowin = (reg & 3) + 8 * (reg >> 2) + 4 * half;
            int row = rt * 32 + rowin;
            float v = fmaxf(acc1[j][reg] + bb, 0.f);
            h1frag[region * RS + row * 8 + off] = f2bf(v);
        }
    }
    __syncthreads();

    // stage 2 on all 4 waves: wave = rt2*2 + ct2 tile (32 rows x 32 cols)
    int rt2 = wave >> 1, ct2 = wave & 1;
    f32x16 acc2 = {};
    #pragma unroll
    for (int s = 0; s < 16; ++s) {
        bf16x8 a = *(bf16x8*)&h1frag[(s * 2 + half) * RS + (rt2 * 32 + l31) * 8];
        bf16x8 b = *(const bf16x8*)(W2f + (size_t)(s * 2 + half) * 512 + (ct2 * 32 + l31) * 8);
        acc2 = __builtin_amdgcn_mfma_f32_32x32x16_bf16(a, b, acc2, 0, 0, 0);
    }

    float bb = b2[ct2 * 32 + l31];
    int ch = ct2 * 32 + l31;
    #pragma unroll
    for (int reg = 0; reg < 16; ++reg) {
        int rowin = (reg & 3) + 8 * (reg >> 2) + 4 * half;
        int row = bm + rt2 * 32 + rowin;
        if (row < M) {
            float h = acc2[reg] + bb;
            g[(size_t)row * 64 + ch] = f2bf(dinv[row] * h);
        }
    }
}

// ---- one hop (r15): wave per dest; 8 lanes/row dwordx4 (8 ch/lane),
//      8 edges per gather instruction, 16 in flight. Pure gather+store. ----
__global__ __launch_bounds__(256) void spmm5_kernel(
        const int* __restrict__ offs, const int* __restrict__ src,
        const float* __restrict__ dinv,
        const unsigned* __restrict__ gin,    // [n][32] dwords (bf16x2)
        unsigned* __restrict__ gout, int n) {
    int wid = (blockIdx.x * blockDim.x + threadIdx.x) >> 6;
    int lane = threadIdx.x & 63;
    if (wid >= n) return;
    int g = lane >> 3;       // edge slot 0..7
    int q = lane & 7;        // dword quad -> channels 8q..8q+7
    int c = __builtin_amdgcn_readfirstlane(wid);
    int e0 = __builtin_amdgcn_readfirstlane(offs[c]);
    int e1 = __builtin_amdgcn_readfirstlane(offs[c + 1]);

    float a0 = 0.f, a1 = 0.f, a2 = 0.f, a3 = 0.f;
    float a4 = 0.f, a5 = 0.f, a6 = 0.f, a7 = 0.f;
    for (int e = e0; e < e1; e += 16) {
        #pragma unroll
        for (int u = 0; u < 2; ++u) {
            int ei = e + u * 8 + g;
            int ec = ei < e1 ? ei : e1 - 1;
            unsigned m = ei < e1 ? 0xffffffffu : 0u;
            int s = __builtin_nontemporal_load(src + ec);
            uint4 v = *(const uint4*)(gin + (size_t)s * 32 + q * 4);
            v.x &= m; v.y &= m; v.z &= m; v.w &= m;
            a0 += bflo(v.x); a1 += bfhi(v.x);
            a2 += bflo(v.y); a3 += bfhi(v.y);
            a4 += bflo(v.z); a5 += bfhi(v.z);
            a6 += bflo(v.w); a7 += bfhi(v.w);
        }
    }
    // reduce across the 8 edge slots (lane bits 3..5)
    a0 += __shfl_xor(a0, 8, 64); a0 += __shfl_xor(a0, 16, 64); a0 += __shfl_xor(a0, 32, 64);
    a1 += __shfl_xor(a1, 8, 64); a1 += __shfl_xor(a1, 16, 64); a1 += __shfl_xor(a1, 32, 64);
    a2 += __shfl_xor(a2, 8, 64); a2 += __shfl_xor(a2, 16, 64); a2 += __shfl_xor(a2, 32, 64);
    a3 += __shfl_xor(a3, 8, 64); a3 += __shfl_xor(a3, 16, 64); a3 += __shfl_xor(a3, 32, 64);
    a4 += __shfl_xor(a4, 8, 64); a4 += __shfl_xor(a4, 16, 64); a4 += __shfl_xor(a4, 32, 64);
    a5 += __shfl_xor(a5, 8, 64); a5 += __shfl_xor(a5, 16, 64); a5 += __shfl_xor(a5, 32, 64);
    a6 += __shfl_xor(a6, 8, 64); a6 += __shfl_xor(a6, 16, 64); a6 += __shfl_xor(a6, 32, 64);
    a7 += __shfl_xor(a7, 8, 64); a7 += __shfl_xor(a7, 16, 64); a7 += __shfl_xor(a7, 32, 64);

    uint4 sv = *(const uint4*)(gin + (size_t)c * 32 + q * 4);   // self-loop
    float dc = dinv[c];
    float h0 = dc * (a0 + bflo(sv.x)), h1 = dc * (a1 + bfhi(sv.x));
    float h2 = dc * (a2 + bflo(sv.y)), h3 = dc * (a3 + bfhi(sv.y));
    float h4 = dc * (a4 + bflo(sv.z)), h5 = dc * (a5 + bfhi(sv.z));
    float h6 = dc * (a6 + bflo(sv.w)), h7 = dc * (a7 + bfhi(sv.w));

    if (g == 0) {   // 8 lanes x 16B = full 128B row
        uint4 gw;
        gw.x = (unsigned)f2bf(dc * h0) | ((unsigned)f2bf(dc * h1) << 16);
        gw.y = (unsigned)f2bf(dc * h2) | ((unsigned)f2bf(dc * h3) << 16);
        gw.z = (unsigned)f2bf(dc * h4) | ((unsigned)f2bf(dc * h5) << 16);
        gw.w = (unsigned)f2bf(dc * h6) | ((unsigned)f2bf(dc * h7) << 16);
        *(uint4*)(gout + (size_t)c * 32 + q * 4) = gw;
    }
}

// ---- final pooling: out[c] = sum_k sigmoid(h_k . pw + pb) * h_k,
//      h_k = sdeg[c] * preds_k[c]. 16 threads per node (4 ch each). ----
__global__ void pool_kernel(const unsigned* __restrict__ preds, size_t pstride,
                            const float* __restrict__ sdeg,
                            const float* __restrict__ pw, const float* __restrict__ pb,
                            float* __restrict__ out, int n) {
    int tid = blockIdx.x * 256 + threadIdx.x;
    int c = tid >> 4;
    if (c >= n) return;
    int w = tid & 15;               // channels w*4 .. w*4+3
    float sd = sdeg[c];
    float4 pv = *(const float4*)(pw + w * 4);
    float pbv = pb[0];
    float o0 = 0.f, o1 = 0.f, o2 = 0.f, o3 = 0.f;
    for (int k = 0; k <= 10; ++k) {
        uint2 v = *(const uint2*)(preds + (size_t)k * pstride + (size_t)c * 32 + w * 2);
        float h0 = sd * bflo(v.x), h1 = sd * bfhi(v.x);
        float h2 = sd * bflo(v.y), h3 = sd * bfhi(v.y);
        float d = h0 * pv.x + h1 * pv.y + h2 * pv.z + h3 * pv.w;
        d += __shfl_xor(d, 1, 64);
        d += __shfl_xor(d, 2, 64);
        d += __shfl_xor(d, 4, 64);
        d += __shfl_xor(d, 8, 64);
        float sg = 1.f / (1.f + __expf(-(d + pbv)));
        o0 += sg * h0; o1 += sg * h1; o2 += sg * h2; o3 += sg * h3;
    }
    float4 o = make_float4(o0, o1, o2, o3);
    *(float4*)(out + (size_t)c * 64 + w * 4) = o;
}

extern "C" void kernel_launch(void* const* d_in, const int* in_sizes, int n_in,
                              void* d_out, int out_size, void* d_ws, size_t ws_size,
                              hipStream_t stream) {
    const float* x  = (const float*)d_in[0];
    const int* eidx = (const int*)d_in[1];
    const float* W1 = (const float*)d_in[2];
    const float* b1 = (const float*)d_in[3];
    const float* W2 = (const float*)d_in[4];
    const float* b2 = (const float*)d_in[5];
    const float* pw = (const float*)d_in[6];
    const float* pb = (const float*)d_in[7];
    float* out = (float*)d_out;

    const int N = in_sizes[0] / 256;
    const int E = in_sizes[1] / 2;
    const int NB = (N + 255) >> 8;              // buckets of 256 dest nodes
    const int EPB = (E + NBLK - 1) / NBLK;      // edges per passA/passB block
    const int M = NB * NBLK;                    // blk_cnt entries

    size_t woff = 0;
    auto alloc = [&](size_t bytes) -> void* {
        void* p = (char*)d_ws + woff;
        woff += (bytes + 255) & ~(size_t)255;
        return p;
    };
    int*   sflag   = (int*)alloc(4);
    int*   cnt     = (int*)alloc((size_t)N * 4);
    float* dinv    = (float*)alloc((size_t)N * 4);
    float* sdeg    = (float*)alloc((size_t)N * 4);
    int*   offs    = (int*)alloc(((size_t)N + 1) * 4);
    int*   bsums   = (int*)alloc(1024 * 4);
    int*   bsums2  = (int*)alloc(1024 * 4);
    int*   pbase   = (int*)alloc(((size_t)M + 1) * 4);
    int*   csr_src = (int*)alloc((size_t)E * 4);
    unsigned short* W1f = (unsigned short*)alloc((size_t)256 * 256 * 2);
    unsigned short* W2f = (unsigned short*)alloc((size_t)64 * 256 * 2);
    const size_t planeB = (size_t)N * 64 * 2;         // bytes per preds plane
    unsigned short* preds = (unsigned short*)alloc(11 * planeB);
    // pairs overlaid on preds planes 1-2: dead after passC; plane1 first
    // written by hop 1 (after mlp). E*8 <= 10*planeB for avg degree <= 80.
    int2* pairs = (int2*)((char*)preds + planeB);

    detect_kernel<<<1, 256, 0, stream>>>((const unsigned*)eidx, sflag);

    // build: histogram -> scan -> pair scatter -> node counts -> offs -> CSR
    passA_kernel<<<NBLK, 256, 0, stream>>>(eidx, sflag, pbase, E, NB, EPB);
    int nb2 = (M + 1023) / 1024;
    scan1_kernel<<<nb2, 256, 0, stream>>>(pbase, pbase, bsums2, M);
    scan2g_kernel<<<1, 256, 0, stream>>>(bsums2, nb2);
    scan3_kernel<<<nb2, 256, 0, stream>>>(pbase, bsums2, M, E);
    passB_kernel<<<NBLK, 256, 0, stream>>>(eidx, sflag, pbase, pairs, E, NB, EPB);
    passD_kernel<<<NB, 256, 0, stream>>>(pairs, pbase, cnt, N, NB);
    dinv_kernel<<<(N + 255) / 256, 256, 0, stream>>>(cnt, dinv, sdeg, N);
    int nb1 = (N + 1023) / 1024;
    scan1_kernel<<<nb1, 256, 0, stream>>>(cnt, offs, bsums, N);
    scan2g_kernel<<<1, 256, 0, stream>>>(bsums, nb1);
    scan3_kernel<<<nb1, 256, 0, stream>>>(offs, bsums, N, E);
    passC_kernel<<<NB, 256, 0, stream>>>(pairs, pbase, offs, csr_src, N, NB);

    // MLP (fused): writes preds plane 0 = bf16(dinv*h0)
    wconv_kernel<<<(256 * 256 + 255) / 256, 256, 0, stream>>>(W1, W1f, 256, 256);
    wconv_kernel<<<(64 * 256 + 255) / 256, 256, 0, stream>>>(W2, W2f, 256, 64);
    int gb = (N + 63) / 64;
    mlp_fused<<<gb, 256, 0, stream>>>(x, W1f, b1, W2f, b2, dinv, preds, N);

    // propagation: hop k reads plane k-1, writes plane k (pure gather)
    int nwb = (N + 3) / 4;   // 4 waves (=4 dests) per 256-thread block
    for (int k = 1; k <= 10; ++k) {
        const unsigned* gi = (const unsigned*)((char*)preds + (size_t)(k - 1) * planeB);
        unsigned* go = (unsigned*)((char*)preds + (size_t)k * planeB);
        spmm5_kernel<<<nwb, 256, 0, stream>>>(offs, csr_src, dinv, gi, go, N);
    }

    // final pooling over all 11 planes
    pool_kernel<<<(N * 16 + 255) / 256, 256, 0, stream>>>(
        (const unsigned*)preds, planeB / 4, sdeg, pw, pb, out, N);
}